// Round 6
// baseline (146.979 us; speedup 1.0000x reference)
//
#include <hip/hip_runtime.h>
#include <hip/hip_bf16.h>
#include <stdint.h>

#define T_TOKENS 8192
#define D_DIM 1024
#define H_DIM 2048
#define N_EXPERTS 8

typedef __attribute__((ext_vector_type(8))) short bf16x8;
typedef __attribute__((ext_vector_type(4))) float f32x4;

typedef __attribute__((address_space(1))) const void* gptr_t;
typedef __attribute__((address_space(3))) void* lptr_t;

__device__ __forceinline__ unsigned short f2bf(float f) {
  union { float f; unsigned int u; } x; x.f = f;
  unsigned int r = x.u + 0x7FFFu + ((x.u >> 16) & 1u);
  return (unsigned short)(r >> 16);
}
__device__ __forceinline__ float bf2f(unsigned short b) {
  union { unsigned int u; float f; } x; x.u = ((unsigned int)b) << 16;
  return x.f;
}

__device__ __forceinline__ void gload16(const void* g, void* l) {
  __builtin_amdgcn_global_load_lds((gptr_t)g, (lptr_t)l, 16, 0, 0);
}

// Sync discipline (rule #18: sched_barrier after inline-asm waits / raw barriers)
#define SBAR()  do { __builtin_amdgcn_s_barrier(); __builtin_amdgcn_sched_barrier(0); } while (0)
#define LGKM0() do { asm volatile("s_waitcnt lgkmcnt(0)" ::: "memory"); __builtin_amdgcn_sched_barrier(0); } while (0)
#define LGKM8() do { asm volatile("s_waitcnt lgkmcnt(8)" ::: "memory"); __builtin_amdgcn_sched_barrier(0); } while (0)
#define VMW(n)  do { __builtin_amdgcn_sched_barrier(0); asm volatile("s_waitcnt vmcnt(" #n ")" ::: "memory"); } while (0)

// ---------------------------------------------------------------------------
// fp32 -> bf16 conversion — round-1 structure (measured ~36us for all three).
// ---------------------------------------------------------------------------
__global__ void cvt_f32_bf16_kernel(const float* __restrict__ in,
                                    unsigned short* __restrict__ out, int n) {
  int tid = blockIdx.x * blockDim.x + threadIdx.x;
  int stride = gridDim.x * blockDim.x;
  for (int i = tid * 4; i < n; i += stride * 4) {
    const float4 v = *reinterpret_cast<const float4*>(in + i);
    ushort4 o;
    o.x = f2bf(v.x); o.y = f2bf(v.y); o.z = f2bf(v.z); o.w = f2bf(v.w);
    *reinterpret_cast<ushort4*>(out + i) = o;
  }
}

// ---------------------------------------------------------------------------
// Grouped GEMM, deep-pipelined (T3+T4): C[M,N] = A[M,K] @ B[e][N,K]^T.
// BM=256 BN=128 BK=64. 8 waves 4Mx2N (per-wave 64x64, acc[4][4]).
// LDS ring-of-3 K-tile buffers: lA 3x[256][64] (96KB) + lB 3x[128][64] (48KB).
// Per K-tile: ONE vmcnt(9) (2-tile prefetch depth, never drains below 9 in
// steady state), 2 barriers, 16+16 MFMA with partial lgkmcnt(8) so the kk1
// ds_reads' latency hides under the kk0 MFMA cluster.
// Race-safety (proven orderings):
//  - arrival: tile t staged at t-2; VMW(9) at t leaves exactly tiles t+1 (6)
//    + t+2-partial (3) outstanding => forces tile t; SBAR before any read.
//  - WAR: buf((t+2)%3) last ds_read at tile t-1; those reads are drained by
//    t-1's lgkmcnt(0) before t-1's end-SBAR; stage issues at t come after it.
// XOR swizzle ([256][64] rows = 128B = full bank wrap): LDS cell (row,c16)
// holds global granule c16 ^ (row&7); staging pre-swizzles the GLOBAL source
// (rule #21), reads use granule (kk*4 + lane>>4) ^ (l15&7) -> ~2-way = free.
// FUSE=true: O=bf16(relu(bf16(acc))^2) -> OB. FUSE=false: O=f32(bf16(acc)) -> OF.
// ---------------------------------------------------------------------------
template <int K, int N, bool FUSE>
__global__ __launch_bounds__(512, 2)
void ggemm(const unsigned short* __restrict__ A,
           const unsigned short* __restrict__ B,
           const int* __restrict__ counts,
           unsigned short* __restrict__ OB,
           float* __restrict__ OF) {
  constexpr int NT = K / 64;
  constexpr int NCB = N / 128;
  constexpr int AT = 256 * 64;  // shorts per A tile buffer
  constexpr int BT = 128 * 64;  // shorts per B tile buffer
  __shared__ short lA[3 * AT];  // 96 KB
  __shared__ short lB[3 * BT];  // 48 KB

  const int tid = threadIdx.x;
  const int wid = tid >> 6, lane = tid & 63;
  const int wr = wid >> 1, wc = wid & 1;
  const int bid = blockIdx.x;
  const int cb = bid % NCB, rb = bid / NCB;  // same-cb blocks share an XCD (NCB%8==0)
  const int r0 = rb * 256, c0 = cb * 128;

  int csum[N_EXPERTS + 1];
  csum[0] = 0;
  for (int e = 0; e < N_EXPERTS; ++e) csum[e + 1] = csum[e] + counts[e];
  int eLo = 0;
  while (eLo < N_EXPERTS - 1 && csum[eLo + 1] <= r0) ++eLo;
  int eHi = eLo;
  while (eHi < N_EXPERTS - 1 && csum[eHi + 1] < r0 + 256) ++eHi;

  // staging: per gload line, lane L covers row (L>>3), 16B granule (L&7);
  // global source granule pre-swizzled: (L&7) ^ (L>>3)
  const int srow = lane >> 3;
  const int scol = ((lane & 7) ^ srow) * 8;
  const int aw = wid * 32;  // A stage row base per wave (4 lines of 8 rows)
  const int bw = wid * 16;  // B stage row base per wave (2 lines of 8 rows)
  const int l15 = lane & 15;
  const int rg = (lane >> 4) & 3;
  const int g0 = ((rg) ^ (l15 & 7)) * 8;        // kk0 read granule (shorts)
  const int g1 = ((4 + rg) ^ (l15 & 7)) * 8;    // kk1 read granule

  const unsigned short* Ab = A + (size_t)r0 * K;

  for (int e = eLo; e <= eHi; ++e) {
    const unsigned short* Bb = B + (size_t)e * N * K + (size_t)c0 * K;
    f32x4 acc[4][4];
#pragma unroll
    for (int mi = 0; mi < 4; ++mi)
#pragma unroll
      for (int ni = 0; ni < 4; ++ni) acc[mi][ni] = (f32x4){0.f, 0.f, 0.f, 0.f};

#define SA(T, J, BN) gload16(Ab + (size_t)(aw + (J) * 8 + srow) * K + (size_t)(T) * 64 + scol, \
                             &lA[(BN) * AT + (aw + (J) * 8) * 64])
#define SB_(T, J, BN) gload16(Bb + (size_t)(bw + (J) * 8 + srow) * K + (size_t)(T) * 64 + scol, \
                              &lB[(BN) * BT + (bw + (J) * 8) * 64])
#define RD(BI, G, FA, FB) do { \
    _Pragma("unroll") for (int m_ = 0; m_ < 4; ++m_) \
      FA[m_] = *(const bf16x8*)&lA[(BI) * AT + (wr * 64 + m_ * 16 + l15) * 64 + (G)]; \
    _Pragma("unroll") for (int n_ = 0; n_ < 4; ++n_) \
      FB[n_] = *(const bf16x8*)&lB[(BI) * BT + (wc * 64 + n_ * 16 + l15) * 64 + (G)]; \
  } while (0)
#define MM(FA, FB) do { \
    __builtin_amdgcn_s_setprio(1); \
    _Pragma("unroll") for (int m_ = 0; m_ < 4; ++m_) \
      _Pragma("unroll") for (int n_ = 0; n_ < 4; ++n_) \
        acc[m_][n_] = __builtin_amdgcn_mfma_f32_16x16x32_bf16(FA[m_], FB[n_], acc[m_][n_], 0, 0, 0); \
    __builtin_amdgcn_s_setprio(0); \
  } while (0)
// One K-tile: phase A {stage 3 lines of tile T+2, VMW, SBAR, read both kk,
// lgkmcnt(8), 16 MFMA kk0}; phase B {stage 3 lines, lgkmcnt(0), 16 MFMA kk1, SBAR}.
#define KT(T, BI, BN, WAIT, ST) do { \
    bf16x8 fa0[4], fb0[4], fa1[4], fb1[4]; \
    if (ST) { SA((T) + 2, 0, BN); SA((T) + 2, 1, BN); SB_((T) + 2, 0, BN); } \
    WAIT; \
    SBAR(); \
    RD(BI, g0, fa0, fb0); \
    RD(BI, g1, fa1, fb1); \
    LGKM8(); \
    MM(fa0, fb0); \
    if (ST) { SA((T) + 2, 2, BN); SA((T) + 2, 3, BN); SB_((T) + 2, 1, BN); } \
    LGKM0(); \
    MM(fa1, fb1); \
    SBAR(); \
  } while (0)

    // prologue: stage tiles 0 and 1 fully (12 lines/wave); no wait needed here —
    // the first in-loop VMW(9) forces tile 0's arrival.
    SA(0, 0, 0); SA(0, 1, 0); SA(0, 2, 0); SA(0, 3, 0); SB_(0, 0, 0); SB_(0, 1, 0);
    SA(1, 0, 1); SA(1, 1, 1); SA(1, 2, 1); SA(1, 3, 1); SB_(1, 0, 1); SB_(1, 1, 1);

    int bi = 0;
#pragma unroll 1
    for (int t = 0; t < NT - 2; ++t) {
      const int bn = (bi >= 1) ? bi - 1 : 2;  // (bi+2)%3
      KT(t, bi, bn, VMW(9), true);
      bi = (bi >= 2) ? 0 : bi + 1;
    }
    KT(NT - 2, bi, 0, VMW(6), false);
    bi = (bi >= 2) ? 0 : bi + 1;
    KT(NT - 1, bi, 0, VMW(0), false);

    // epilogue: C/D layout col=lane&15, row=(lane>>4)*4+reg (m89/m91 verified)
    const int segLo = csum[e], segHi = csum[e + 1];
#pragma unroll
    for (int mi = 0; mi < 4; ++mi) {
      const int rowb = r0 + wr * 64 + mi * 16 + ((lane >> 4) << 2);
#pragma unroll
      for (int ni = 0; ni < 4; ++ni) {
        const int col = c0 + wc * 64 + ni * 16 + l15;
#pragma unroll
        for (int r = 0; r < 4; ++r) {
          const int gr = rowb + r;
          if (gr >= segLo && gr < segHi) {
            if (FUSE) {
              float h = bf2f(f2bf(acc[mi][ni][r]));
              h = h > 0.f ? h : 0.f;
              OB[(size_t)gr * N + col] = f2bf(h * h);
            } else {
              OF[(size_t)gr * N + col] = bf2f(f2bf(acc[mi][ni][r]));
            }
          }
        }
      }
    }
#undef SA
#undef SB_
#undef RD
#undef MM
#undef KT
  }
}

extern "C" void kernel_launch(void* const* d_in, const int* in_sizes, int n_in,
                              void* d_out, int out_size, void* d_ws, size_t ws_size,
                              hipStream_t stream) {
  const float* x = (const float*)d_in[0];
  const float* w_up = (const float*)d_in[1];
  const float* w_down = (const float*)d_in[2];
  const int* counts = (const int*)d_in[3];
  float* out = (float*)d_out;

  char* ws = (char*)d_ws;
  unsigned short* xb  = (unsigned short*)(ws);
  unsigned short* wub = (unsigned short*)(ws + (size_t)16 * 1024 * 1024);
  unsigned short* wdb = (unsigned short*)(ws + (size_t)48 * 1024 * 1024);
  unsigned short* hsq = (unsigned short*)(ws + (size_t)80 * 1024 * 1024);

  cvt_f32_bf16_kernel<<<2048, 256, 0, stream>>>(x, xb, T_TOKENS * D_DIM);
  cvt_f32_bf16_kernel<<<2048, 256, 0, stream>>>(w_up, wub, N_EXPERTS * H_DIM * D_DIM);
  cvt_f32_bf16_kernel<<<2048, 256, 0, stream>>>(w_down, wdb, N_EXPERTS * D_DIM * H_DIM);

  // GEMM1: hsq = bf16(relu(bf16(x @ w_up^T))^2)  (T,H); grid 32 rb x 16 cb
  ggemm<D_DIM, H_DIM, true>
      <<<(T_TOKENS / 256) * (H_DIM / 128), 512, 0, stream>>>(xb, wub, counts, hsq, nullptr);
  // GEMM2: out = f32(bf16(hsq @ w_down^T))  (T,D); grid 32 rb x 8 cb
  ggemm<H_DIM, D_DIM, false>
      <<<(T_TOKENS / 256) * (D_DIM / 128), 512, 0, stream>>>(hsq, wdb, counts, nullptr, out);
}